// Round 5
// baseline (193.804 us; speedup 1.0000x reference)
//
#include <hip/hip_runtime.h>
#include <hip/hip_bf16.h>

// Causal self-attention: qkv = x@w_qkv + b_qkv; flash-attn (causal); out = att@w_proj + b_proj
// B=4, T=2048, C=1024, H=16, D=64. All matmuls bf16 MFMA 16x16x32, fp32 accumulate.
// R4: flash VALU diet — softmax scale folded into w_qkv Q-columns (S arrives in log2
//     domain), lane-local defer-max check, deferred cross-lane l-reduce, f32x4 packed
//     softmax math, strength-reduced global pointers. GEMMs: XCD-aware block swizzle.

typedef __bf16 bf16x8 __attribute__((ext_vector_type(8)));
typedef float f32x4 __attribute__((ext_vector_type(4)));
typedef unsigned short u16x8 __attribute__((ext_vector_type(8)));
typedef unsigned short u16x4 __attribute__((ext_vector_type(4)));
typedef unsigned int u32;

#define LOG2E 1.44269504088896340736f
#define NEG_INF (-__builtin_inff())

#define AS_GLOBAL(p) ((const __attribute__((address_space(1))) u32*)(p))
#define AS_LDS(p) ((__attribute__((address_space(3))) u32*)(p))

__device__ __forceinline__ unsigned short f2bf(float f) {
  unsigned int u = __builtin_bit_cast(unsigned int, f);
  u += 0x7fff + ((u >> 16) & 1);   // RNE
  return (unsigned short)(u >> 16);
}

__device__ __forceinline__ u32 cvt_pk_bf16(float lo, float hi) {
  u32 r;
  asm("v_cvt_pk_bf16_f32 %0, %1, %2" : "=v"(r) : "v"(lo), "v"(hi));
  return r;
}

__device__ __forceinline__ bf16x8 ld_frag(const unsigned short* p) {
  return __builtin_bit_cast(bf16x8, *reinterpret_cast<const u16x8*>(p));
}

// ---- fp32 -> bf16 elementwise (x) ----
__global__ void k_convert(const float* __restrict__ in, unsigned short* __restrict__ out, int n4) {
  int i = blockIdx.x * blockDim.x + threadIdx.x;
  int stride = gridDim.x * blockDim.x;
  for (; i < n4; i += stride) {
    float4 v = reinterpret_cast<const float4*>(in)[i];
    u16x4 o = { f2bf(v.x), f2bf(v.y), f2bf(v.z), f2bf(v.w) };
    reinterpret_cast<u16x4*>(out)[i] = o;
  }
}

// ---- fp32 [K][N] -> bf16 [N][K] transpose; rows n < scaleN of output scaled by scl ----
__global__ void k_transpose(const float* __restrict__ in, unsigned short* __restrict__ out,
                            int K, int N, int scaleN, float scl) {
  __shared__ float tile[32][33];
  int n0 = blockIdx.x * 32, k0 = blockIdx.y * 32;
  int tx = threadIdx.x & 31, ty = threadIdx.x >> 5;  // 32 x 8
#pragma unroll
  for (int i = 0; i < 4; i++)
    tile[ty + i * 8][tx] = in[(size_t)(k0 + ty + i * 8) * N + n0 + tx];
  __syncthreads();
#pragma unroll
  for (int i = 0; i < 4; i++) {
    int n = n0 + ty + i * 8;
    float v = tile[tx][ty + i * 8];
    if (n < scaleN) v *= scl;
    out[(size_t)n * K + k0 + tx] = f2bf(v);
  }
}

// ---- bias prep: first scaleN entries scaled ----
__global__ void k_scale_bias(const float* __restrict__ in, float* __restrict__ out,
                             int n, int scaleN, float scl) {
  int i = blockIdx.x * blockDim.x + threadIdx.x;
  if (i < n) out[i] = (i < scaleN) ? in[i] * scl : in[i];
}

// ---- bf16 GEMM (m97 structure + XCD swizzle): C = A @ Bt^T + bias ----
template <bool BF16_OUT>
__global__ __launch_bounds__(256) void k_gemm(
    const unsigned short* __restrict__ A, const unsigned short* __restrict__ Bt,
    const float* __restrict__ bias, void* __restrict__ Cv, int M, int N, int K) {
  constexpr int BK = 64;
  __shared__ unsigned short Asm[128][BK];
  __shared__ unsigned short Bsm[128][BK];
  const int tid = threadIdx.x;
  const int lane = tid & 63, w = tid >> 6;
  const int wr = w >> 1, wc = w & 1;

  // XCD-aware swizzle: each XCD gets a contiguous chunk, column-major over tiles
  // (chunk = 64 row-tiles x few col-tiles -> B-panel L2-resident per XCD)
  int bid = blockIdx.y * gridDim.x + blockIdx.x;
  int cpx = (gridDim.x * gridDim.y) >> 3;
  int swz = (bid & 7) * cpx + (bid >> 3);
  const int brow = (swz % gridDim.x) * 128, bcol = (swz / gridDim.x) * 128;

  const int r0 = lane & 15, kq = lane >> 4;

  f32x4 acc[4][4] = {};

  const int srow = lane >> 3, scol = (lane & 7) * 8;

  for (int k0 = 0; k0 < K; k0 += BK) {
    __syncthreads();
#pragma unroll
    for (int q = 0; q < 4; q++) {
      int c = w * 4 + q;
      const unsigned short* ga = &A[(size_t)(brow + c * 8 + srow) * K + k0 + scol];
      const unsigned short* gb = &Bt[(size_t)(bcol + c * 8 + srow) * K + k0 + scol];
      __builtin_amdgcn_global_load_lds(AS_GLOBAL(ga), AS_LDS(&Asm[c * 8][0]), 16, 0, 0);
      __builtin_amdgcn_global_load_lds(AS_GLOBAL(gb), AS_LDS(&Bsm[c * 8][0]), 16, 0, 0);
    }
    __syncthreads();
#pragma unroll
    for (int c = 0; c < 2; c++) {
      bf16x8 af[4], bfr[4];
#pragma unroll
      for (int m = 0; m < 4; m++)
        af[m] = ld_frag(&Asm[wr * 64 + m * 16 + r0][c * 32 + kq * 8]);
#pragma unroll
      for (int n = 0; n < 4; n++)
        bfr[n] = ld_frag(&Bsm[wc * 64 + n * 16 + r0][c * 32 + kq * 8]);
      __builtin_amdgcn_s_setprio(1);
#pragma unroll
      for (int m = 0; m < 4; m++)
#pragma unroll
        for (int n = 0; n < 4; n++)
          acc[m][n] = __builtin_amdgcn_mfma_f32_16x16x32_bf16(af[m], bfr[n], acc[m][n], 0, 0, 0);
      __builtin_amdgcn_s_setprio(0);
    }
  }

  const int orow = kq * 4;
#pragma unroll
  for (int n = 0; n < 4; n++) {
#pragma unroll
    for (int m = 0; m < 4; m++) {
      int col = bcol + wc * 64 + n * 16 + r0;
      float bv = bias[col];
#pragma unroll
      for (int r = 0; r < 4; r++) {
        int row = brow + wr * 64 + m * 16 + orow + r;
        float v = acc[m][n][r] + bv;
        if (BF16_OUT)
          ((unsigned short*)Cv)[(size_t)row * N + col] = f2bf(v);
        else
          ((float*)Cv)[(size_t)row * N + col] = v;
      }
    }
  }
}

// ---- causal flash attention ----
// Q pre-scaled by 0.125*log2e (folded into w_qkv) => S^T lands in log2 domain.
__global__ __launch_bounds__(256) void k_flash(const unsigned short* __restrict__ qkv,
                                               unsigned short* __restrict__ att, int T) {
  constexpr int C3 = 3072, C = 1024;
  __shared__ unsigned short Ksm[2][64][72];   // [buf][tk][d]
  __shared__ unsigned short Vsm[2][64][72];   // [buf][d][tk ^ (d&56)]

  const int tid = threadIdx.x, lane = tid & 63, w = tid >> 6;
  const int bh = blockIdx.x;
  const int qt = gridDim.y - 1 - blockIdx.y;  // long blocks first
  const int b = bh >> 4, h = bh & 15;
  const int q0 = qt * 64;
  const int r0 = lane & 15, kq = lane >> 4;

  const size_t rowbase = (size_t)b * T * C3;

  bf16x8 qf[2];
  {
    const unsigned short* qp = &qkv[rowbase + (size_t)(q0 + w * 16 + r0) * C3 + h * 64];
    qf[0] = ld_frag(&qp[kq * 8]);
    qf[1] = ld_frag(&qp[32 + kq * 8]);
  }

  f32x4 accO[4] = {};
  f32x4 ls4 = {0.f, 0.f, 0.f, 0.f};   // per-lane partial exp-sums (deferred reduce)
  float m_run = NEG_INF;
  const int q_my = q0 + w * 16 + r0;

  const int stk = tid >> 3, sd8 = (tid & 7) * 8;
  const unsigned short* kbase = &qkv[rowbase + (size_t)stk * C3 + h * 64 + sd8 + C];
  constexpr size_t PSTRIDE = (size_t)32 * C3;

  u16x8 kreg[2], vreg[2];
  auto LOADT = [&](size_t off) {
#pragma unroll
    for (int p = 0; p < 2; p++) {
      kreg[p] = *reinterpret_cast<const u16x8*>(kbase + off + p * PSTRIDE);
      vreg[p] = *reinterpret_cast<const u16x8*>(kbase + off + p * PSTRIDE + C);
    }
  };
  auto WRITET = [&](int buf) {
#pragma unroll
    for (int p = 0; p < 2; p++) {
      int tkk = p * 32 + stk;
      *reinterpret_cast<u16x8*>(&Ksm[buf][tkk][sd8]) = kreg[p];
      int tkx = tkk ^ sd8;
#pragma unroll
      for (int i = 0; i < 8; i++) Vsm[buf][sd8 + i][tkx] = vreg[p][i];
    }
  };

  auto TILE = [&](int buf, int k0, bool diag) {
    const unsigned short(*Ks)[72] = Ksm[buf];
    const unsigned short(*Vs)[72] = Vsm[buf];

    // S^T = K @ Q^T (already log2-scaled via Q)
    f32x4 st[4];
    __builtin_amdgcn_s_setprio(1);
#pragma unroll
    for (int s = 0; s < 4; s++) {
      f32x4 a = {};
      a = __builtin_amdgcn_mfma_f32_16x16x32_bf16(ld_frag(&Ks[s * 16 + r0][kq * 8]), qf[0], a, 0, 0, 0);
      a = __builtin_amdgcn_mfma_f32_16x16x32_bf16(ld_frag(&Ks[s * 16 + r0][32 + kq * 8]), qf[1], a, 0, 0, 0);
      st[s] = a;
    }
    __builtin_amdgcn_s_setprio(0);

    f32x4 sv4[4];
    if (diag) {
#pragma unroll
      for (int s = 0; s < 4; s++)
#pragma unroll
        for (int r = 0; r < 4; r++) {
          int kg = k0 + s * 16 + kq * 4 + r;
          sv4[s][r] = (kg > q_my) ? NEG_INF : st[s][r];
        }
    } else {
#pragma unroll
      for (int s = 0; s < 4; s++) sv4[s] = st[s];
    }

    // lane-local max (packed); cross-lane reduce deferred to rescale branch
    f32x4 m4 = __builtin_elementwise_max(__builtin_elementwise_max(sv4[0], sv4[1]),
                                         __builtin_elementwise_max(sv4[2], sv4[3]));
    float mx = fmaxf(fmaxf(m4[0], m4[1]), fmaxf(m4[2], m4[3]));

    if (__any(mx > m_run + 8.f)) {
      mx = fmaxf(mx, __shfl_xor(mx, 16));
      mx = fmaxf(mx, __shfl_xor(mx, 32));
      float mn = fmaxf(m_run, mx);
      float corr = exp2f(m_run - mn);
      m_run = mn;
      ls4 *= corr;
      float cq[4];
#pragma unroll
      for (int r = 0; r < 4; r++) cq[r] = __shfl(corr, kq * 4 + r);
#pragma unroll
      for (int n = 0; n < 4; n++)
#pragma unroll
        for (int r = 0; r < 4; r++) accO[n][r] *= cq[r];
    }

    f32x4 pv4[4];
#pragma unroll
    for (int s = 0; s < 4; s++) {
      f32x4 d = sv4[s] - m_run;
      f32x4 p = { exp2f(d[0]), exp2f(d[1]), exp2f(d[2]), exp2f(d[3]) };
      pv4[s] = p;
      ls4 += p;
    }

    // PV
    __builtin_amdgcn_s_setprio(1);
#pragma unroll
    for (int t = 0; t < 2; t++) {
      u32 pd[4];
      pd[0] = cvt_pk_bf16(pv4[2 * t][0], pv4[2 * t][1]);
      pd[1] = cvt_pk_bf16(pv4[2 * t][2], pv4[2 * t][3]);
      pd[2] = cvt_pk_bf16(pv4[2 * t + 1][0], pv4[2 * t + 1][1]);
      pd[3] = cvt_pk_bf16(pv4[2 * t + 1][2], pv4[2 * t + 1][3]);
      bf16x8 pa = __builtin_bit_cast(bf16x8, *reinterpret_cast<u16x8*>(pd));
#pragma unroll
      for (int n = 0; n < 4; n++) {
        int d = n * 16 + r0;
        int swzb = d & 56;
        const u16x4 lo = *reinterpret_cast<const u16x4*>(&Vs[d][(t * 32 + kq * 4) ^ swzb]);
        const u16x4 hi = *reinterpret_cast<const u16x4*>(&Vs[d][(t * 32 + 16 + kq * 4) ^ swzb]);
        u16x8 vb;
#pragma unroll
        for (int i = 0; i < 4; i++) { vb[i] = lo[i]; vb[4 + i] = hi[i]; }
        accO[n] = __builtin_amdgcn_mfma_f32_16x16x32_bf16(
            pa, __builtin_bit_cast(bf16x8, vb), accO[n], 0, 0, 0);
      }
    }
    __builtin_amdgcn_s_setprio(0);
  };

  int buf = 0;
  LOADT(0);
  WRITET(0);
  size_t koff = (size_t)64 * C3;
  for (int kt = 0; kt < qt; kt++) {
    __syncthreads();
    LOADT(koff);
    koff += (size_t)64 * C3;
    TILE(buf, kt * 64, false);
    WRITET(buf ^ 1);
    buf ^= 1;
  }
  __syncthreads();
  TILE(buf, qt * 64, true);

  // epilogue: deferred l reduce, normalize, write att
  float l_run = ls4[0] + ls4[1] + ls4[2] + ls4[3];
  l_run += __shfl_xor(l_run, 16);
  l_run += __shfl_xor(l_run, 32);
  float lr[4];
#pragma unroll
  for (int r = 0; r < 4; r++) lr[r] = 1.f / __shfl(l_run, kq * 4 + r);
#pragma unroll
  for (int n = 0; n < 4; n++) {
#pragma unroll
    for (int r = 0; r < 4; r++) {
      int qrow = q0 + w * 16 + kq * 4 + r;
      float v = accO[n][r] * lr[r];
      att[((size_t)b * T + qrow) * C + h * 64 + n * 16 + r0] = f2bf(v);
    }
  }
}

extern "C" void kernel_launch(void* const* d_in, const int* in_sizes, int n_in,
                              void* d_out, int out_size, void* d_ws, size_t ws_size,
                              hipStream_t stream) {
  const float* x = (const float*)d_in[0];
  const float* w_qkv = (const float*)d_in[1];
  const float* b_qkv = (const float*)d_in[2];
  const float* w_proj = (const float*)d_in[3];
  const float* b_proj = (const float*)d_in[4];

  constexpr int B = 4, T = 2048, C = 1024, C3 = 3072;
  constexpr int M = B * T;  // 8192
  constexpr float SCL = 0.125f * LOG2E;

  unsigned short* x_bf = (unsigned short*)d_ws;            // M*C
  unsigned short* wqkvT = x_bf + (size_t)M * C;            // C3*C
  unsigned short* wprojT = wqkvT + (size_t)C3 * C;         // C*C
  unsigned short* qkv = wprojT + (size_t)C * C;            // M*C3
  unsigned short* att = qkv + (size_t)M * C3;              // M*C
  float* bias_s = (float*)(att + (size_t)M * C);           // C3 floats

  hipLaunchKernelGGL(k_convert, dim3(2048), dim3(256), 0, stream, x, x_bf, M * C / 4);
  hipLaunchKernelGGL(k_transpose, dim3(C3 / 32, C / 32), dim3(256), 0, stream,
                     w_qkv, wqkvT, C, C3, C, SCL);
  hipLaunchKernelGGL(k_transpose, dim3(C / 32, C / 32), dim3(256), 0, stream,
                     w_proj, wprojT, C, C, 0, 1.f);
  hipLaunchKernelGGL(k_scale_bias, dim3((C3 + 255) / 256), dim3(256), 0, stream,
                     b_qkv, bias_s, C3, C, SCL);
  hipLaunchKernelGGL((k_gemm<true>), dim3(M / 128, C3 / 128), dim3(256), 0, stream,
                     x_bf, wqkvT, bias_s, (void*)qkv, M, C3, C);
  hipLaunchKernelGGL(k_flash, dim3(64, 32), dim3(256), 0, stream, qkv, att, T);
  hipLaunchKernelGGL((k_gemm<false>), dim3(M / 128, C / 128), dim3(256), 0, stream,
                     att, wprojT, b_proj, d_out, M, C, C);
}

// Round 6
// 180.448 us; speedup vs baseline: 1.0740x; 1.0740x over previous
//
#include <hip/hip_runtime.h>
#include <hip/hip_bf16.h>

// Causal self-attention: qkv = x@w_qkv + b_qkv; flash-attn (causal); out = att@w_proj + b_proj
// B=4, T=2048, C=1024, H=16, D=64. All matmuls bf16 MFMA 16x16x32, fp32 accumulate.
// R5: flash — 2 q-subtiles per wave (32 q-rows), 128-row blocks: K-frag/V-frag/staging
//     amortized over 2x MFMA. GEMM swizzle reverted (r4 regression: A-panel streamed
//     through 4MB L2 per column chunk).

typedef __bf16 bf16x8 __attribute__((ext_vector_type(8)));
typedef float f32x4 __attribute__((ext_vector_type(4)));
typedef unsigned short u16x8 __attribute__((ext_vector_type(8)));
typedef unsigned short u16x4 __attribute__((ext_vector_type(4)));
typedef unsigned int u32;

#define LOG2E 1.44269504088896340736f
#define NEG_INF (-__builtin_inff())

#define AS_GLOBAL(p) ((const __attribute__((address_space(1))) u32*)(p))
#define AS_LDS(p) ((__attribute__((address_space(3))) u32*)(p))

__device__ __forceinline__ unsigned short f2bf(float f) {
  unsigned int u = __builtin_bit_cast(unsigned int, f);
  u += 0x7fff + ((u >> 16) & 1);   // RNE
  return (unsigned short)(u >> 16);
}

__device__ __forceinline__ u32 cvt_pk_bf16(float lo, float hi) {
  u32 r;
  asm("v_cvt_pk_bf16_f32 %0, %1, %2" : "=v"(r) : "v"(lo), "v"(hi));
  return r;
}

__device__ __forceinline__ bf16x8 ld_frag(const unsigned short* p) {
  return __builtin_bit_cast(bf16x8, *reinterpret_cast<const u16x8*>(p));
}

// ---- fp32 -> bf16 elementwise (x) ----
__global__ void k_convert(const float* __restrict__ in, unsigned short* __restrict__ out, int n4) {
  int i = blockIdx.x * blockDim.x + threadIdx.x;
  int stride = gridDim.x * blockDim.x;
  for (; i < n4; i += stride) {
    float4 v = reinterpret_cast<const float4*>(in)[i];
    u16x4 o = { f2bf(v.x), f2bf(v.y), f2bf(v.z), f2bf(v.w) };
    reinterpret_cast<u16x4*>(out)[i] = o;
  }
}

// ---- fp32 [K][N] -> bf16 [N][K] transpose; rows n < scaleN of output scaled by scl ----
__global__ void k_transpose(const float* __restrict__ in, unsigned short* __restrict__ out,
                            int K, int N, int scaleN, float scl) {
  __shared__ float tile[32][33];
  int n0 = blockIdx.x * 32, k0 = blockIdx.y * 32;
  int tx = threadIdx.x & 31, ty = threadIdx.x >> 5;  // 32 x 8
#pragma unroll
  for (int i = 0; i < 4; i++)
    tile[ty + i * 8][tx] = in[(size_t)(k0 + ty + i * 8) * N + n0 + tx];
  __syncthreads();
#pragma unroll
  for (int i = 0; i < 4; i++) {
    int n = n0 + ty + i * 8;
    float v = tile[tx][ty + i * 8];
    if (n < scaleN) v *= scl;
    out[(size_t)n * K + k0 + tx] = f2bf(v);
  }
}

// ---- bias prep: first scaleN entries scaled ----
__global__ void k_scale_bias(const float* __restrict__ in, float* __restrict__ out,
                             int n, int scaleN, float scl) {
  int i = blockIdx.x * blockDim.x + threadIdx.x;
  if (i < n) out[i] = (i < scaleN) ? in[i] * scl : in[i];
}

// ---- bf16 GEMM (m97 structure): C = A @ Bt^T + bias ----
template <bool BF16_OUT>
__global__ __launch_bounds__(256) void k_gemm(
    const unsigned short* __restrict__ A, const unsigned short* __restrict__ Bt,
    const float* __restrict__ bias, void* __restrict__ Cv, int M, int N, int K) {
  constexpr int BK = 64;
  __shared__ unsigned short Asm[128][BK];
  __shared__ unsigned short Bsm[128][BK];
  const int tid = threadIdx.x;
  const int lane = tid & 63, w = tid >> 6;
  const int wr = w >> 1, wc = w & 1;
  const int brow = blockIdx.x * 128, bcol = blockIdx.y * 128;
  const int r0 = lane & 15, kq = lane >> 4;

  f32x4 acc[4][4] = {};

  const int srow = lane >> 3, scol = (lane & 7) * 8;

  for (int k0 = 0; k0 < K; k0 += BK) {
    __syncthreads();
#pragma unroll
    for (int q = 0; q < 4; q++) {
      int c = w * 4 + q;
      const unsigned short* ga = &A[(size_t)(brow + c * 8 + srow) * K + k0 + scol];
      const unsigned short* gb = &Bt[(size_t)(bcol + c * 8 + srow) * K + k0 + scol];
      __builtin_amdgcn_global_load_lds(AS_GLOBAL(ga), AS_LDS(&Asm[c * 8][0]), 16, 0, 0);
      __builtin_amdgcn_global_load_lds(AS_GLOBAL(gb), AS_LDS(&Bsm[c * 8][0]), 16, 0, 0);
    }
    __syncthreads();
#pragma unroll
    for (int c = 0; c < 2; c++) {
      bf16x8 af[4], bfr[4];
#pragma unroll
      for (int m = 0; m < 4; m++)
        af[m] = ld_frag(&Asm[wr * 64 + m * 16 + r0][c * 32 + kq * 8]);
#pragma unroll
      for (int n = 0; n < 4; n++)
        bfr[n] = ld_frag(&Bsm[wc * 64 + n * 16 + r0][c * 32 + kq * 8]);
      __builtin_amdgcn_s_setprio(1);
#pragma unroll
      for (int m = 0; m < 4; m++)
#pragma unroll
        for (int n = 0; n < 4; n++)
          acc[m][n] = __builtin_amdgcn_mfma_f32_16x16x32_bf16(af[m], bfr[n], acc[m][n], 0, 0, 0);
      __builtin_amdgcn_s_setprio(0);
    }
  }

  const int orow = kq * 4;
#pragma unroll
  for (int n = 0; n < 4; n++) {
#pragma unroll
    for (int m = 0; m < 4; m++) {
      int col = bcol + wc * 64 + n * 16 + r0;
      float bv = bias[col];
#pragma unroll
      for (int r = 0; r < 4; r++) {
        int row = brow + wr * 64 + m * 16 + orow + r;
        float v = acc[m][n][r] + bv;
        if (BF16_OUT)
          ((unsigned short*)Cv)[(size_t)row * N + col] = f2bf(v);
        else
          ((float*)Cv)[(size_t)row * N + col] = v;
      }
    }
  }
}

// ---- causal flash attention: 4 waves x 32 q-rows (2 subtiles), 128-row blocks ----
// Q pre-scaled by 0.125*log2e (folded into w_qkv) => S^T lands in log2 domain.
__global__ __launch_bounds__(256, 3) void k_flash(const unsigned short* __restrict__ qkv,
                                                  unsigned short* __restrict__ att, int T) {
  constexpr int C3 = 3072, C = 1024;
  __shared__ unsigned short Ksm[2][64][72];   // [buf][tk][d]
  __shared__ unsigned short Vsm[2][64][72];   // [buf][d][tk ^ (d&56)]

  const int tid = threadIdx.x, lane = tid & 63, w = tid >> 6;
  const int bh = blockIdx.x;
  const int qtp = gridDim.y - 1 - blockIdx.y;  // long blocks first
  const int b = bh >> 4, h = bh & 15;
  const int q0 = qtp * 128;
  const int r0 = lane & 15, kq = lane >> 4;

  const size_t rowbase = (size_t)b * T * C3;
  const int qb0 = q0 + w * 32, qb1 = qb0 + 16;

  bf16x8 qf[2][2];
  {
    const unsigned short* qp0 = &qkv[rowbase + (size_t)(qb0 + r0) * C3 + h * 64];
    qf[0][0] = ld_frag(&qp0[kq * 8]);
    qf[0][1] = ld_frag(&qp0[32 + kq * 8]);
    const unsigned short* qp1 = qp0 + (size_t)16 * C3;
    qf[1][0] = ld_frag(&qp1[kq * 8]);
    qf[1][1] = ld_frag(&qp1[32 + kq * 8]);
  }

  f32x4 accO[2][4] = {};
  f32x4 ls4[2] = {{0.f,0.f,0.f,0.f},{0.f,0.f,0.f,0.f}};
  float m_run[2] = {NEG_INF, NEG_INF};

  const int stk = tid >> 3, sd8 = (tid & 7) * 8;
  const unsigned short* kbase = &qkv[rowbase + (size_t)stk * C3 + h * 64 + sd8 + C];
  constexpr size_t PSTRIDE = (size_t)32 * C3;

  u16x8 kreg[2], vreg[2];
  auto LOADT = [&](size_t off) {
#pragma unroll
    for (int p = 0; p < 2; p++) {
      kreg[p] = *reinterpret_cast<const u16x8*>(kbase + off + p * PSTRIDE);
      vreg[p] = *reinterpret_cast<const u16x8*>(kbase + off + p * PSTRIDE + C);
    }
  };
  auto WRITET = [&](int buf) {
#pragma unroll
    for (int p = 0; p < 2; p++) {
      int tkk = p * 32 + stk;
      *reinterpret_cast<u16x8*>(&Ksm[buf][tkk][sd8]) = kreg[p];
      int tkx = tkk ^ sd8;
#pragma unroll
      for (int i = 0; i < 8; i++) Vsm[buf][sd8 + i][tkx] = vreg[p][i];
    }
  };

  auto TILE = [&](int buf, int k0) {
    if (k0 > qb1 + 15) return;   // whole wave past its causal range
    const unsigned short(*Ks)[72] = Ksm[buf];
    const unsigned short(*Vs)[72] = Vsm[buf];

    // S^T = K @ Q^T for both subtiles, K-frags shared
    f32x4 st[2][4];
    __builtin_amdgcn_s_setprio(1);
#pragma unroll
    for (int s = 0; s < 4; s++) {
      bf16x8 kf0 = ld_frag(&Ks[s * 16 + r0][kq * 8]);
      bf16x8 kf1 = ld_frag(&Ks[s * 16 + r0][32 + kq * 8]);
#pragma unroll
      for (int u = 0; u < 2; u++) {
        f32x4 a = {};
        a = __builtin_amdgcn_mfma_f32_16x16x32_bf16(kf0, qf[u][0], a, 0, 0, 0);
        a = __builtin_amdgcn_mfma_f32_16x16x32_bf16(kf1, qf[u][1], a, 0, 0, 0);
        st[u][s] = a;
      }
    }
    __builtin_amdgcn_s_setprio(0);

    // softmax per subtile (in-register, lane-local rows)
    u32 pd[2][2][4];
#pragma unroll
    for (int u = 0; u < 2; u++) {
      const int qbu = u ? qb1 : qb0;
      const int qmy = qbu + r0;
      f32x4 sv[4];
      if (k0 + 63 > qbu) {
#pragma unroll
        for (int s = 0; s < 4; s++)
#pragma unroll
          for (int r = 0; r < 4; r++) {
            int kg = k0 + s * 16 + kq * 4 + r;
            sv[s][r] = (kg > qmy) ? NEG_INF : st[u][s][r];
          }
      } else {
#pragma unroll
        for (int s = 0; s < 4; s++) sv[s] = st[u][s];
      }

      f32x4 m4 = __builtin_elementwise_max(__builtin_elementwise_max(sv[0], sv[1]),
                                           __builtin_elementwise_max(sv[2], sv[3]));
      float mx = fmaxf(fmaxf(m4[0], m4[1]), fmaxf(m4[2], m4[3]));

      if (__any(mx > m_run[u] + 8.f)) {
        mx = fmaxf(mx, __shfl_xor(mx, 16));
        mx = fmaxf(mx, __shfl_xor(mx, 32));
        float mn = fmaxf(m_run[u], mx);
        float corr = exp2f(m_run[u] - mn);
        m_run[u] = mn;
        ls4[u] *= corr;
        float cq[4];
#pragma unroll
        for (int r = 0; r < 4; r++) cq[r] = __shfl(corr, kq * 4 + r);
#pragma unroll
        for (int n = 0; n < 4; n++)
#pragma unroll
          for (int r = 0; r < 4; r++) accO[u][n][r] *= cq[r];
      }

#pragma unroll
      for (int s = 0; s < 4; s++) {
        f32x4 d = sv[s] - m_run[u];
        f32x4 p = { exp2f(d[0]), exp2f(d[1]), exp2f(d[2]), exp2f(d[3]) };
        sv[s] = p;
        ls4[u] += p;
      }
      pd[u][0][0] = cvt_pk_bf16(sv[0][0], sv[0][1]);
      pd[u][0][1] = cvt_pk_bf16(sv[0][2], sv[0][3]);
      pd[u][0][2] = cvt_pk_bf16(sv[1][0], sv[1][1]);
      pd[u][0][3] = cvt_pk_bf16(sv[1][2], sv[1][3]);
      pd[u][1][0] = cvt_pk_bf16(sv[2][0], sv[2][1]);
      pd[u][1][1] = cvt_pk_bf16(sv[2][2], sv[2][3]);
      pd[u][1][2] = cvt_pk_bf16(sv[3][0], sv[3][1]);
      pd[u][1][3] = cvt_pk_bf16(sv[3][2], sv[3][3]);
    }

    // PV for both subtiles, V-frags shared
    __builtin_amdgcn_s_setprio(1);
#pragma unroll
    for (int t = 0; t < 2; t++) {
      bf16x8 pa0 = __builtin_bit_cast(bf16x8, *reinterpret_cast<u16x8*>(pd[0][t]));
      bf16x8 pa1 = __builtin_bit_cast(bf16x8, *reinterpret_cast<u16x8*>(pd[1][t]));
#pragma unroll
      for (int n = 0; n < 4; n++) {
        int d = n * 16 + r0;
        int swzb = d & 56;
        const u16x4 lo = *reinterpret_cast<const u16x4*>(&Vs[d][(t * 32 + kq * 4) ^ swzb]);
        const u16x4 hi = *reinterpret_cast<const u16x4*>(&Vs[d][(t * 32 + 16 + kq * 4) ^ swzb]);
        u16x8 vbw;
#pragma unroll
        for (int i = 0; i < 4; i++) { vbw[i] = lo[i]; vbw[4 + i] = hi[i]; }
        bf16x8 vb = __builtin_bit_cast(bf16x8, vbw);
        accO[0][n] = __builtin_amdgcn_mfma_f32_16x16x32_bf16(pa0, vb, accO[0][n], 0, 0, 0);
        accO[1][n] = __builtin_amdgcn_mfma_f32_16x16x32_bf16(pa1, vb, accO[1][n], 0, 0, 0);
      }
    }
    __builtin_amdgcn_s_setprio(0);
  };

  int buf = 0;
  LOADT(0);
  WRITET(0);
  size_t koff = (size_t)64 * C3;
  const int nkt = (q0 + 128) >> 6;
  for (int kt = 0; kt < nkt - 1; kt++) {
    __syncthreads();
    LOADT(koff);
    koff += (size_t)64 * C3;
    TILE(buf, kt * 64);
    WRITET(buf ^ 1);
    buf ^= 1;
  }
  __syncthreads();
  TILE(buf, (nkt - 1) * 64);

  // epilogue
#pragma unroll
  for (int u = 0; u < 2; u++) {
    const int qbu = u ? qb1 : qb0;
    float l = ls4[u][0] + ls4[u][1] + ls4[u][2] + ls4[u][3];
    l += __shfl_xor(l, 16);
    l += __shfl_xor(l, 32);
    float lr[4];
#pragma unroll
    for (int r = 0; r < 4; r++) lr[r] = 1.f / __shfl(l, kq * 4 + r);
#pragma unroll
    for (int n = 0; n < 4; n++) {
#pragma unroll
      for (int r = 0; r < 4; r++) {
        int qrow = qbu + kq * 4 + r;
        float v = accO[u][n][r] * lr[r];
        att[((size_t)b * T + qrow) * C + h * 64 + n * 16 + r0] = f2bf(v);
      }
    }
  }
}

extern "C" void kernel_launch(void* const* d_in, const int* in_sizes, int n_in,
                              void* d_out, int out_size, void* d_ws, size_t ws_size,
                              hipStream_t stream) {
  const float* x = (const float*)d_in[0];
  const float* w_qkv = (const float*)d_in[1];
  const float* b_qkv = (const float*)d_in[2];
  const float* w_proj = (const float*)d_in[3];
  const float* b_proj = (const float*)d_in[4];

  constexpr int B = 4, T = 2048, C = 1024, C3 = 3072;
  constexpr int M = B * T;  // 8192
  constexpr float SCL = 0.125f * LOG2E;

  unsigned short* x_bf = (unsigned short*)d_ws;            // M*C
  unsigned short* wqkvT = x_bf + (size_t)M * C;            // C3*C
  unsigned short* wprojT = wqkvT + (size_t)C3 * C;         // C*C
  unsigned short* qkv = wprojT + (size_t)C * C;            // M*C3
  unsigned short* att = qkv + (size_t)M * C3;              // M*C
  float* bias_s = (float*)(att + (size_t)M * C);           // C3 floats

  hipLaunchKernelGGL(k_convert, dim3(2048), dim3(256), 0, stream, x, x_bf, M * C / 4);
  hipLaunchKernelGGL(k_transpose, dim3(C3 / 32, C / 32), dim3(256), 0, stream,
                     w_qkv, wqkvT, C, C3, C, SCL);
  hipLaunchKernelGGL(k_transpose, dim3(C / 32, C / 32), dim3(256), 0, stream,
                     w_proj, wprojT, C, C, 0, 1.f);
  hipLaunchKernelGGL(k_scale_bias, dim3((C3 + 255) / 256), dim3(256), 0, stream,
                     b_qkv, bias_s, C3, C, SCL);
  hipLaunchKernelGGL((k_gemm<true>), dim3(M / 128, C3 / 128), dim3(256), 0, stream,
                     x_bf, wqkvT, bias_s, (void*)qkv, M, C3, C);
  hipLaunchKernelGGL(k_flash, dim3(64, 16), dim3(256), 0, stream, qkv, att, T);
  hipLaunchKernelGGL((k_gemm<false>), dim3(M / 128, C / 128), dim3(256), 0, stream,
                     att, wprojT, b_proj, d_out, M, C, C);
}

// Round 8
// 179.688 us; speedup vs baseline: 1.0786x; 1.0042x over previous
//
#include <hip/hip_runtime.h>
#include <hip/hip_bf16.h>

// Causal self-attention: qkv = x@w_qkv + b_qkv; flash-attn (causal); out = att@w_proj + b_proj
// B=4, T=2048, C=1024, H=16, D=64. All matmuls bf16 MFMA 16x16x32, fp32 accumulate.
// R7: BISECT r6's correctness failure. Keep: gemm T2 swizzle (inverse-swizzled global
//     source + linear gload_lds dest + XOR'd fragment read; algebra triple-checked).
//     Revert: k_flash to r5's proven version (register V scatter; the tr_b16 path is
//     the prime suspect — unverifiable HW semantics).

typedef __bf16 bf16x8 __attribute__((ext_vector_type(8)));
typedef float f32x4 __attribute__((ext_vector_type(4)));
typedef unsigned short u16x8 __attribute__((ext_vector_type(8)));
typedef unsigned short u16x4 __attribute__((ext_vector_type(4)));
typedef unsigned int u32;

#define LOG2E 1.44269504088896340736f
#define NEG_INF (-__builtin_inff())

#define AS_GLOBAL(p) ((const __attribute__((address_space(1))) u32*)(p))
#define AS_LDS(p) ((__attribute__((address_space(3))) u32*)(p))

__device__ __forceinline__ unsigned short f2bf(float f) {
  unsigned int u = __builtin_bit_cast(unsigned int, f);
  u += 0x7fff + ((u >> 16) & 1);   // RNE
  return (unsigned short)(u >> 16);
}

__device__ __forceinline__ u32 cvt_pk_bf16(float lo, float hi) {
  u32 r;
  asm("v_cvt_pk_bf16_f32 %0, %1, %2" : "=v"(r) : "v"(lo), "v"(hi));
  return r;
}

__device__ __forceinline__ bf16x8 ld_frag(const unsigned short* p) {
  return __builtin_bit_cast(bf16x8, *reinterpret_cast<const u16x8*>(p));
}

// ---- fp32 -> bf16 elementwise (x) ----
__global__ void k_convert(const float* __restrict__ in, unsigned short* __restrict__ out, int n4) {
  int i = blockIdx.x * blockDim.x + threadIdx.x;
  int stride = gridDim.x * blockDim.x;
  for (; i < n4; i += stride) {
    float4 v = reinterpret_cast<const float4*>(in)[i];
    u16x4 o = { f2bf(v.x), f2bf(v.y), f2bf(v.z), f2bf(v.w) };
    reinterpret_cast<u16x4*>(out)[i] = o;
  }
}

// ---- fp32 [K][N] -> bf16 [N][K] transpose; rows n < scaleN of output scaled by scl ----
__global__ void k_transpose(const float* __restrict__ in, unsigned short* __restrict__ out,
                            int K, int N, int scaleN, float scl) {
  __shared__ float tile[32][33];
  int n0 = blockIdx.x * 32, k0 = blockIdx.y * 32;
  int tx = threadIdx.x & 31, ty = threadIdx.x >> 5;  // 32 x 8
#pragma unroll
  for (int i = 0; i < 4; i++)
    tile[ty + i * 8][tx] = in[(size_t)(k0 + ty + i * 8) * N + n0 + tx];
  __syncthreads();
#pragma unroll
  for (int i = 0; i < 4; i++) {
    int n = n0 + ty + i * 8;
    float v = tile[tx][ty + i * 8];
    if (n < scaleN) v *= scl;
    out[(size_t)n * K + k0 + tx] = f2bf(v);
  }
}

// ---- bias prep: first scaleN entries scaled ----
__global__ void k_scale_bias(const float* __restrict__ in, float* __restrict__ out,
                             int n, int scaleN, float scl) {
  int i = blockIdx.x * blockDim.x + threadIdx.x;
  if (i < n) out[i] = (i < scaleN) ? in[i] * scl : in[i];
}

// ---- bf16 GEMM (m97 structure + T2 swizzle): C = A @ Bt^T + bias ----
// LDS (row, slot) holds global (row, slot ^ ((row>>2)&3)); read XORs the same term.
template <bool BF16_OUT>
__global__ __launch_bounds__(256) void k_gemm(
    const unsigned short* __restrict__ A, const unsigned short* __restrict__ Bt,
    const float* __restrict__ bias, void* __restrict__ Cv, int M, int N, int K) {
  constexpr int BK = 64;
  __shared__ unsigned short Asm[128][BK];
  __shared__ unsigned short Bsm[128][BK];
  const int tid = threadIdx.x;
  const int lane = tid & 63, w = tid >> 6;
  const int wr = w >> 1, wc = w & 1;
  const int brow = blockIdx.x * 128, bcol = blockIdx.y * 128;
  const int r0 = lane & 15, kq = lane >> 4;

  f32x4 acc[4][4] = {};

  const int srow = lane >> 3;
  const int swa = ((r0 >> 2) & 3) << 3;  // read-side XOR (elements)

  for (int k0 = 0; k0 < K; k0 += BK) {
    __syncthreads();
#pragma unroll
    for (int q2 = 0; q2 < 4; q2++) {
      int c = w * 4 + q2;
      // inverse-swizzled source slot so linear gload_lds lands data swizzled
      int scol = ((lane & 7) ^ ((2 * c + (lane >> 5)) & 3)) * 8;
      const unsigned short* ga = &A[(size_t)(brow + c * 8 + srow) * K + k0 + scol];
      const unsigned short* gb = &Bt[(size_t)(bcol + c * 8 + srow) * K + k0 + scol];
      __builtin_amdgcn_global_load_lds(AS_GLOBAL(ga), AS_LDS(&Asm[c * 8][0]), 16, 0, 0);
      __builtin_amdgcn_global_load_lds(AS_GLOBAL(gb), AS_LDS(&Bsm[c * 8][0]), 16, 0, 0);
    }
    __syncthreads();
#pragma unroll
    for (int c = 0; c < 2; c++) {
      bf16x8 af[4], bfr[4];
#pragma unroll
      for (int m = 0; m < 4; m++)
        af[m] = ld_frag(&Asm[wr * 64 + m * 16 + r0][(c * 32 + kq * 8) ^ swa]);
#pragma unroll
      for (int n = 0; n < 4; n++)
        bfr[n] = ld_frag(&Bsm[wc * 64 + n * 16 + r0][(c * 32 + kq * 8) ^ swa]);
      __builtin_amdgcn_s_setprio(1);
#pragma unroll
      for (int m = 0; m < 4; m++)
#pragma unroll
        for (int n = 0; n < 4; n++)
          acc[m][n] = __builtin_amdgcn_mfma_f32_16x16x32_bf16(af[m], bfr[n], acc[m][n], 0, 0, 0);
      __builtin_amdgcn_s_setprio(0);
    }
  }

  const int orow = kq * 4;
#pragma unroll
  for (int n = 0; n < 4; n++) {
#pragma unroll
    for (int m = 0; m < 4; m++) {
      int col = bcol + wc * 64 + n * 16 + r0;
      float bv = bias[col];
#pragma unroll
      for (int r = 0; r < 4; r++) {
        int row = brow + wr * 64 + m * 16 + orow + r;
        float v = acc[m][n][r] + bv;
        if (BF16_OUT)
          ((unsigned short*)Cv)[(size_t)row * N + col] = f2bf(v);
        else
          ((float*)Cv)[(size_t)row * N + col] = v;
      }
    }
  }
}

// ---- causal flash attention: 4 waves x 32 q-rows (2 subtiles), 128-row blocks ----
// (r5-proven version) Q pre-scaled by 0.125*log2e => S^T lands in log2 domain.
__global__ __launch_bounds__(256, 3) void k_flash(const unsigned short* __restrict__ qkv,
                                                  unsigned short* __restrict__ att, int T) {
  constexpr int C3 = 3072, C = 1024;
  __shared__ unsigned short Ksm[2][64][72];   // [buf][tk][d]
  __shared__ unsigned short Vsm[2][64][72];   // [buf][d][tk ^ (d&56)]

  const int tid = threadIdx.x, lane = tid & 63, w = tid >> 6;
  const int bh = blockIdx.x;
  const int qtp = gridDim.y - 1 - blockIdx.y;  // long blocks first
  const int b = bh >> 4, h = bh & 15;
  const int q0 = qtp * 128;
  const int r0 = lane & 15, kq = lane >> 4;

  const size_t rowbase = (size_t)b * T * C3;
  const int qb0 = q0 + w * 32, qb1 = qb0 + 16;

  bf16x8 qf[2][2];
  {
    const unsigned short* qp0 = &qkv[rowbase + (size_t)(qb0 + r0) * C3 + h * 64];
    qf[0][0] = ld_frag(&qp0[kq * 8]);
    qf[0][1] = ld_frag(&qp0[32 + kq * 8]);
    const unsigned short* qp1 = qp0 + (size_t)16 * C3;
    qf[1][0] = ld_frag(&qp1[kq * 8]);
    qf[1][1] = ld_frag(&qp1[32 + kq * 8]);
  }

  f32x4 accO[2][4] = {};
  f32x4 ls4[2] = {{0.f,0.f,0.f,0.f},{0.f,0.f,0.f,0.f}};
  float m_run[2] = {NEG_INF, NEG_INF};

  const int stk = tid >> 3, sd8 = (tid & 7) * 8;
  const unsigned short* kbase = &qkv[rowbase + (size_t)stk * C3 + h * 64 + sd8 + C];
  constexpr size_t PSTRIDE = (size_t)32 * C3;

  u16x8 kreg[2], vreg[2];
  auto LOADT = [&](size_t off) {
#pragma unroll
    for (int p = 0; p < 2; p++) {
      kreg[p] = *reinterpret_cast<const u16x8*>(kbase + off + p * PSTRIDE);
      vreg[p] = *reinterpret_cast<const u16x8*>(kbase + off + p * PSTRIDE + C);
    }
  };
  auto WRITET = [&](int buf) {
#pragma unroll
    for (int p = 0; p < 2; p++) {
      int tkk = p * 32 + stk;
      *reinterpret_cast<u16x8*>(&Ksm[buf][tkk][sd8]) = kreg[p];
      int tkx = tkk ^ sd8;
#pragma unroll
      for (int i = 0; i < 8; i++) Vsm[buf][sd8 + i][tkx] = vreg[p][i];
    }
  };

  auto TILE = [&](int buf, int k0) {
    if (k0 > qb1 + 15) return;   // whole wave past its causal range
    const unsigned short(*Ks)[72] = Ksm[buf];
    const unsigned short(*Vs)[72] = Vsm[buf];

    // S^T = K @ Q^T for both subtiles, K-frags shared
    f32x4 st[2][4];
    __builtin_amdgcn_s_setprio(1);
#pragma unroll
    for (int s = 0; s < 4; s++) {
      bf16x8 kf0 = ld_frag(&Ks[s * 16 + r0][kq * 8]);
      bf16x8 kf1 = ld_frag(&Ks[s * 16 + r0][32 + kq * 8]);
#pragma unroll
      for (int u = 0; u < 2; u++) {
        f32x4 a = {};
        a = __builtin_amdgcn_mfma_f32_16x16x32_bf16(kf0, qf[u][0], a, 0, 0, 0);
        a = __builtin_amdgcn_mfma_f32_16x16x32_bf16(kf1, qf[u][1], a, 0, 0, 0);
        st[u][s] = a;
      }
    }
    __builtin_amdgcn_s_setprio(0);

    // softmax per subtile (in-register, lane-local rows)
    u32 pd[2][2][4];
#pragma unroll
    for (int u = 0; u < 2; u++) {
      const int qbu = u ? qb1 : qb0;
      const int qmy = qbu + r0;
      f32x4 sv[4];
      if (k0 + 63 > qbu) {
#pragma unroll
        for (int s = 0; s < 4; s++)
#pragma unroll
          for (int r = 0; r < 4; r++) {
            int kg = k0 + s * 16 + kq * 4 + r;
            sv[s][r] = (kg > qmy) ? NEG_INF : st[u][s][r];
          }
      } else {
#pragma unroll
        for (int s = 0; s < 4; s++) sv[s] = st[u][s];
      }

      f32x4 m4 = __builtin_elementwise_max(__builtin_elementwise_max(sv[0], sv[1]),
                                           __builtin_elementwise_max(sv[2], sv[3]));
      float mx = fmaxf(fmaxf(m4[0], m4[1]), fmaxf(m4[2], m4[3]));

      if (__any(mx > m_run[u] + 8.f)) {
        mx = fmaxf(mx, __shfl_xor(mx, 16));
        mx = fmaxf(mx, __shfl_xor(mx, 32));
        float mn = fmaxf(m_run[u], mx);
        float corr = exp2f(m_run[u] - mn);
        m_run[u] = mn;
        ls4[u] *= corr;
        float cq[4];
#pragma unroll
        for (int r = 0; r < 4; r++) cq[r] = __shfl(corr, kq * 4 + r);
#pragma unroll
        for (int n = 0; n < 4; n++)
#pragma unroll
          for (int r = 0; r < 4; r++) accO[u][n][r] *= cq[r];
      }

#pragma unroll
      for (int s = 0; s < 4; s++) {
        f32x4 d = sv[s] - m_run[u];
        f32x4 p = { exp2f(d[0]), exp2f(d[1]), exp2f(d[2]), exp2f(d[3]) };
        sv[s] = p;
        ls4[u] += p;
      }
      pd[u][0][0] = cvt_pk_bf16(sv[0][0], sv[0][1]);
      pd[u][0][1] = cvt_pk_bf16(sv[0][2], sv[0][3]);
      pd[u][0][2] = cvt_pk_bf16(sv[1][0], sv[1][1]);
      pd[u][0][3] = cvt_pk_bf16(sv[1][2], sv[1][3]);
      pd[u][1][0] = cvt_pk_bf16(sv[2][0], sv[2][1]);
      pd[u][1][1] = cvt_pk_bf16(sv[2][2], sv[2][3]);
      pd[u][1][2] = cvt_pk_bf16(sv[3][0], sv[3][1]);
      pd[u][1][3] = cvt_pk_bf16(sv[3][2], sv[3][3]);
    }

    // PV for both subtiles, V-frags shared
    __builtin_amdgcn_s_setprio(1);
#pragma unroll
    for (int t = 0; t < 2; t++) {
      bf16x8 pa0 = __builtin_bit_cast(bf16x8, *reinterpret_cast<u16x8*>(pd[0][t]));
      bf16x8 pa1 = __builtin_bit_cast(bf16x8, *reinterpret_cast<u16x8*>(pd[1][t]));
#pragma unroll
      for (int n = 0; n < 4; n++) {
        int d = n * 16 + r0;
        int swzb = d & 56;
        const u16x4 lo = *reinterpret_cast<const u16x4*>(&Vs[d][(t * 32 + kq * 4) ^ swzb]);
        const u16x4 hi = *reinterpret_cast<const u16x4*>(&Vs[d][(t * 32 + 16 + kq * 4) ^ swzb]);
        u16x8 vbw;
#pragma unroll
        for (int i = 0; i < 4; i++) { vbw[i] = lo[i]; vbw[4 + i] = hi[i]; }
        bf16x8 vb = __builtin_bit_cast(bf16x8, vbw);
        accO[0][n] = __builtin_amdgcn_mfma_f32_16x16x32_bf16(pa0, vb, accO[0][n], 0, 0, 0);
        accO[1][n] = __builtin_amdgcn_mfma_f32_16x16x32_bf16(pa1, vb, accO[1][n], 0, 0, 0);
      }
    }
    __builtin_amdgcn_s_setprio(0);
  };

  int buf = 0;
  LOADT(0);
  WRITET(0);
  size_t koff = (size_t)64 * C3;
  const int nkt = (q0 + 128) >> 6;
  for (int kt = 0; kt < nkt - 1; kt++) {
    __syncthreads();
    LOADT(koff);
    koff += (size_t)64 * C3;
    TILE(buf, kt * 64);
    WRITET(buf ^ 1);
    buf ^= 1;
  }
  __syncthreads();
  TILE(buf, (nkt - 1) * 64);

  // epilogue
#pragma unroll
  for (int u = 0; u < 2; u++) {
    const int qbu = u ? qb1 : qb0;
    float l = ls4[u][0] + ls4[u][1] + ls4[u][2] + ls4[u][3];
    l += __shfl_xor(l, 16);
    l += __shfl_xor(l, 32);
    float lr[4];
#pragma unroll
    for (int r = 0; r < 4; r++) lr[r] = 1.f / __shfl(l, kq * 4 + r);
#pragma unroll
    for (int n = 0; n < 4; n++) {
#pragma unroll
      for (int r = 0; r < 4; r++) {
        int qrow = qbu + kq * 4 + r;
        float v = accO[u][n][r] * lr[r];
        att[((size_t)b * T + qrow) * C + h * 64 + n * 16 + r0] = f2bf(v);
      }
    }
  }
}

extern "C" void kernel_launch(void* const* d_in, const int* in_sizes, int n_in,
                              void* d_out, int out_size, void* d_ws, size_t ws_size,
                              hipStream_t stream) {
  const float* x = (const float*)d_in[0];
  const float* w_qkv = (const float*)d_in[1];
  const float* b_qkv = (const float*)d_in[2];
  const float* w_proj = (const float*)d_in[3];
  const float* b_proj = (const float*)d_in[4];

  constexpr int B = 4, T = 2048, C = 1024, C3 = 3072;
  constexpr int M = B * T;  // 8192
  constexpr float SCL = 0.125f * LOG2E;

  unsigned short* x_bf = (unsigned short*)d_ws;            // M*C
  unsigned short* wqkvT = x_bf + (size_t)M * C;            // C3*C
  unsigned short* wprojT = wqkvT + (size_t)C3 * C;         // C*C
  unsigned short* qkv = wprojT + (size_t)C * C;            // M*C3
  unsigned short* att = qkv + (size_t)M * C3;              // M*C
  float* bias_s = (float*)(att + (size_t)M * C);           // C3 floats

  hipLaunchKernelGGL(k_convert, dim3(2048), dim3(256), 0, stream, x, x_bf, M * C / 4);
  hipLaunchKernelGGL(k_transpose, dim3(C3 / 32, C / 32), dim3(256), 0, stream,
                     w_qkv, wqkvT, C, C3, C, SCL);
  hipLaunchKernelGGL(k_transpose, dim3(C / 32, C / 32), dim3(256), 0, stream,
                     w_proj, wprojT, C, C, 0, 1.f);
  hipLaunchKernelGGL(k_scale_bias, dim3((C3 + 255) / 256), dim3(256), 0, stream,
                     b_qkv, bias_s, C3, C, SCL);
  hipLaunchKernelGGL((k_gemm<true>), dim3(M / 128, C3 / 128), dim3(256), 0, stream,
                     x_bf, wqkvT, bias_s, (void*)qkv, M, C3, C);
  hipLaunchKernelGGL(k_flash, dim3(64, 16), dim3(256), 0, stream, qkv, att, T);
  hipLaunchKernelGGL((k_gemm<false>), dim3(M / 128, C / 128), dim3(256), 0, stream,
                     att, wprojT, b_proj, d_out, M, C, C);
}

// Round 9
// 166.897 us; speedup vs baseline: 1.1612x; 1.0766x over previous
//
#include <hip/hip_runtime.h>
#include <hip/hip_bf16.h>

// Causal self-attention: qkv = x@w_qkv + b_qkv; flash-attn (causal); out = att@w_proj + b_proj
// B=4, T=2048, C=1024, H=16, D=64. All matmuls bf16 MFMA 16x16x32, fp32 accumulate.
// R8: GEMM swizzle CORRECTED — r7's ((row>>2)&3) only permuted the kq-occupied slot
//     subspace (PMC-confirmed no-op). Correct form: full 3-bit slot XOR with (row&7):
//     read e ^= (r0&7)<<3; gload source slot (l&7)^(l>>3). 8 lanes/slot over all 8
//     slots = b128 conflict-free optimum. Flash: r5-proven version, untouched.

typedef __bf16 bf16x8 __attribute__((ext_vector_type(8)));
typedef float f32x4 __attribute__((ext_vector_type(4)));
typedef unsigned short u16x8 __attribute__((ext_vector_type(8)));
typedef unsigned short u16x4 __attribute__((ext_vector_type(4)));
typedef unsigned int u32;

#define LOG2E 1.44269504088896340736f
#define NEG_INF (-__builtin_inff())

#define AS_GLOBAL(p) ((const __attribute__((address_space(1))) u32*)(p))
#define AS_LDS(p) ((__attribute__((address_space(3))) u32*)(p))

__device__ __forceinline__ unsigned short f2bf(float f) {
  unsigned int u = __builtin_bit_cast(unsigned int, f);
  u += 0x7fff + ((u >> 16) & 1);   // RNE
  return (unsigned short)(u >> 16);
}

__device__ __forceinline__ u32 cvt_pk_bf16(float lo, float hi) {
  u32 r;
  asm("v_cvt_pk_bf16_f32 %0, %1, %2" : "=v"(r) : "v"(lo), "v"(hi));
  return r;
}

__device__ __forceinline__ bf16x8 ld_frag(const unsigned short* p) {
  return __builtin_bit_cast(bf16x8, *reinterpret_cast<const u16x8*>(p));
}

// ---- fp32 -> bf16 elementwise (x) ----
__global__ void k_convert(const float* __restrict__ in, unsigned short* __restrict__ out, int n4) {
  int i = blockIdx.x * blockDim.x + threadIdx.x;
  int stride = gridDim.x * blockDim.x;
  for (; i < n4; i += stride) {
    float4 v = reinterpret_cast<const float4*>(in)[i];
    u16x4 o = { f2bf(v.x), f2bf(v.y), f2bf(v.z), f2bf(v.w) };
    reinterpret_cast<u16x4*>(out)[i] = o;
  }
}

// ---- fp32 [K][N] -> bf16 [N][K] transpose; rows n < scaleN of output scaled by scl ----
__global__ void k_transpose(const float* __restrict__ in, unsigned short* __restrict__ out,
                            int K, int N, int scaleN, float scl) {
  __shared__ float tile[32][33];
  int n0 = blockIdx.x * 32, k0 = blockIdx.y * 32;
  int tx = threadIdx.x & 31, ty = threadIdx.x >> 5;  // 32 x 8
#pragma unroll
  for (int i = 0; i < 4; i++)
    tile[ty + i * 8][tx] = in[(size_t)(k0 + ty + i * 8) * N + n0 + tx];
  __syncthreads();
#pragma unroll
  for (int i = 0; i < 4; i++) {
    int n = n0 + ty + i * 8;
    float v = tile[tx][ty + i * 8];
    if (n < scaleN) v *= scl;
    out[(size_t)n * K + k0 + tx] = f2bf(v);
  }
}

// ---- bias prep: first scaleN entries scaled ----
__global__ void k_scale_bias(const float* __restrict__ in, float* __restrict__ out,
                             int n, int scaleN, float scl) {
  int i = blockIdx.x * blockDim.x + threadIdx.x;
  if (i < n) out[i] = (i < scaleN) ? in[i] * scl : in[i];
}

// ---- bf16 GEMM (m97 structure + correct T2 swizzle): C = A @ Bt^T + bias ----
// LDS (row, slot) holds global (row, slot ^ (row&7)); slot = 8-elem (16B) unit.
template <bool BF16_OUT>
__global__ __launch_bounds__(256) void k_gemm(
    const unsigned short* __restrict__ A, const unsigned short* __restrict__ Bt,
    const float* __restrict__ bias, void* __restrict__ Cv, int M, int N, int K) {
  constexpr int BK = 64;
  __shared__ unsigned short Asm[128][BK];
  __shared__ unsigned short Bsm[128][BK];
  const int tid = threadIdx.x;
  const int lane = tid & 63, w = tid >> 6;
  const int wr = w >> 1, wc = w & 1;
  const int brow = blockIdx.x * 128, bcol = blockIdx.y * 128;
  const int r0 = lane & 15, kq = lane >> 4;

  f32x4 acc[4][4] = {};

  const int srow = lane >> 3;                       // 0..7 within the 8-row chunk
  const int scol = ((lane & 7) ^ srow) * 8;         // inverse-swizzled source slot
  const int swa = (r0 & 7) << 3;                    // read-side element XOR

  for (int k0 = 0; k0 < K; k0 += BK) {
    __syncthreads();
#pragma unroll
    for (int q2 = 0; q2 < 4; q2++) {
      int c = w * 4 + q2;
      const unsigned short* ga = &A[(size_t)(brow + c * 8 + srow) * K + k0 + scol];
      const unsigned short* gb = &Bt[(size_t)(bcol + c * 8 + srow) * K + k0 + scol];
      __builtin_amdgcn_global_load_lds(AS_GLOBAL(ga), AS_LDS(&Asm[c * 8][0]), 16, 0, 0);
      __builtin_amdgcn_global_load_lds(AS_GLOBAL(gb), AS_LDS(&Bsm[c * 8][0]), 16, 0, 0);
    }
    __syncthreads();
#pragma unroll
    for (int c = 0; c < 2; c++) {
      bf16x8 af[4], bfr[4];
#pragma unroll
      for (int m = 0; m < 4; m++)
        af[m] = ld_frag(&Asm[wr * 64 + m * 16 + r0][(c * 32 + kq * 8) ^ swa]);
#pragma unroll
      for (int n = 0; n < 4; n++)
        bfr[n] = ld_frag(&Bsm[wc * 64 + n * 16 + r0][(c * 32 + kq * 8) ^ swa]);
      __builtin_amdgcn_s_setprio(1);
#pragma unroll
      for (int m = 0; m < 4; m++)
#pragma unroll
        for (int n = 0; n < 4; n++)
          acc[m][n] = __builtin_amdgcn_mfma_f32_16x16x32_bf16(af[m], bfr[n], acc[m][n], 0, 0, 0);
      __builtin_amdgcn_s_setprio(0);
    }
  }

  const int orow = kq * 4;
#pragma unroll
  for (int n = 0; n < 4; n++) {
#pragma unroll
    for (int m = 0; m < 4; m++) {
      int col = bcol + wc * 64 + n * 16 + r0;
      float bv = bias[col];
#pragma unroll
      for (int r = 0; r < 4; r++) {
        int row = brow + wr * 64 + m * 16 + orow + r;
        float v = acc[m][n][r] + bv;
        if (BF16_OUT)
          ((unsigned short*)Cv)[(size_t)row * N + col] = f2bf(v);
        else
          ((float*)Cv)[(size_t)row * N + col] = v;
      }
    }
  }
}

// ---- causal flash attention: 4 waves x 32 q-rows (2 subtiles), 128-row blocks ----
// (r5-proven version) Q pre-scaled by 0.125*log2e => S^T lands in log2 domain.
__global__ __launch_bounds__(256, 3) void k_flash(const unsigned short* __restrict__ qkv,
                                                  unsigned short* __restrict__ att, int T) {
  constexpr int C3 = 3072, C = 1024;
  __shared__ unsigned short Ksm[2][64][72];   // [buf][tk][d]
  __shared__ unsigned short Vsm[2][64][72];   // [buf][d][tk ^ (d&56)]

  const int tid = threadIdx.x, lane = tid & 63, w = tid >> 6;
  const int bh = blockIdx.x;
  const int qtp = gridDim.y - 1 - blockIdx.y;  // long blocks first
  const int b = bh >> 4, h = bh & 15;
  const int q0 = qtp * 128;
  const int r0 = lane & 15, kq = lane >> 4;

  const size_t rowbase = (size_t)b * T * C3;
  const int qb0 = q0 + w * 32, qb1 = qb0 + 16;

  bf16x8 qf[2][2];
  {
    const unsigned short* qp0 = &qkv[rowbase + (size_t)(qb0 + r0) * C3 + h * 64];
    qf[0][0] = ld_frag(&qp0[kq * 8]);
    qf[0][1] = ld_frag(&qp0[32 + kq * 8]);
    const unsigned short* qp1 = qp0 + (size_t)16 * C3;
    qf[1][0] = ld_frag(&qp1[kq * 8]);
    qf[1][1] = ld_frag(&qp1[32 + kq * 8]);
  }

  f32x4 accO[2][4] = {};
  f32x4 ls4[2] = {{0.f,0.f,0.f,0.f},{0.f,0.f,0.f,0.f}};
  float m_run[2] = {NEG_INF, NEG_INF};

  const int stk = tid >> 3, sd8 = (tid & 7) * 8;
  const unsigned short* kbase = &qkv[rowbase + (size_t)stk * C3 + h * 64 + sd8 + C];
  constexpr size_t PSTRIDE = (size_t)32 * C3;

  u16x8 kreg[2], vreg[2];
  auto LOADT = [&](size_t off) {
#pragma unroll
    for (int p = 0; p < 2; p++) {
      kreg[p] = *reinterpret_cast<const u16x8*>(kbase + off + p * PSTRIDE);
      vreg[p] = *reinterpret_cast<const u16x8*>(kbase + off + p * PSTRIDE + C);
    }
  };
  auto WRITET = [&](int buf) {
#pragma unroll
    for (int p = 0; p < 2; p++) {
      int tkk = p * 32 + stk;
      *reinterpret_cast<u16x8*>(&Ksm[buf][tkk][sd8]) = kreg[p];
      int tkx = tkk ^ sd8;
#pragma unroll
      for (int i = 0; i < 8; i++) Vsm[buf][sd8 + i][tkx] = vreg[p][i];
    }
  };

  auto TILE = [&](int buf, int k0) {
    if (k0 > qb1 + 15) return;   // whole wave past its causal range
    const unsigned short(*Ks)[72] = Ksm[buf];
    const unsigned short(*Vs)[72] = Vsm[buf];

    // S^T = K @ Q^T for both subtiles, K-frags shared
    f32x4 st[2][4];
    __builtin_amdgcn_s_setprio(1);
#pragma unroll
    for (int s = 0; s < 4; s++) {
      bf16x8 kf0 = ld_frag(&Ks[s * 16 + r0][kq * 8]);
      bf16x8 kf1 = ld_frag(&Ks[s * 16 + r0][32 + kq * 8]);
#pragma unroll
      for (int u = 0; u < 2; u++) {
        f32x4 a = {};
        a = __builtin_amdgcn_mfma_f32_16x16x32_bf16(kf0, qf[u][0], a, 0, 0, 0);
        a = __builtin_amdgcn_mfma_f32_16x16x32_bf16(kf1, qf[u][1], a, 0, 0, 0);
        st[u][s] = a;
      }
    }
    __builtin_amdgcn_s_setprio(0);

    // softmax per subtile (in-register, lane-local rows)
    u32 pd[2][2][4];
#pragma unroll
    for (int u = 0; u < 2; u++) {
      const int qbu = u ? qb1 : qb0;
      const int qmy = qbu + r0;
      f32x4 sv[4];
      if (k0 + 63 > qbu) {
#pragma unroll
        for (int s = 0; s < 4; s++)
#pragma unroll
          for (int r = 0; r < 4; r++) {
            int kg = k0 + s * 16 + kq * 4 + r;
            sv[s][r] = (kg > qmy) ? NEG_INF : st[u][s][r];
          }
      } else {
#pragma unroll
        for (int s = 0; s < 4; s++) sv[s] = st[u][s];
      }

      f32x4 m4 = __builtin_elementwise_max(__builtin_elementwise_max(sv[0], sv[1]),
                                           __builtin_elementwise_max(sv[2], sv[3]));
      float mx = fmaxf(fmaxf(m4[0], m4[1]), fmaxf(m4[2], m4[3]));

      if (__any(mx > m_run[u] + 8.f)) {
        mx = fmaxf(mx, __shfl_xor(mx, 16));
        mx = fmaxf(mx, __shfl_xor(mx, 32));
        float mn = fmaxf(m_run[u], mx);
        float corr = exp2f(m_run[u] - mn);
        m_run[u] = mn;
        ls4[u] *= corr;
        float cq[4];
#pragma unroll
        for (int r = 0; r < 4; r++) cq[r] = __shfl(corr, kq * 4 + r);
#pragma unroll
        for (int n = 0; n < 4; n++)
#pragma unroll
          for (int r = 0; r < 4; r++) accO[u][n][r] *= cq[r];
      }

#pragma unroll
      for (int s = 0; s < 4; s++) {
        f32x4 d = sv[s] - m_run[u];
        f32x4 p = { exp2f(d[0]), exp2f(d[1]), exp2f(d[2]), exp2f(d[3]) };
        sv[s] = p;
        ls4[u] += p;
      }
      pd[u][0][0] = cvt_pk_bf16(sv[0][0], sv[0][1]);
      pd[u][0][1] = cvt_pk_bf16(sv[0][2], sv[0][3]);
      pd[u][0][2] = cvt_pk_bf16(sv[1][0], sv[1][1]);
      pd[u][0][3] = cvt_pk_bf16(sv[1][2], sv[1][3]);
      pd[u][1][0] = cvt_pk_bf16(sv[2][0], sv[2][1]);
      pd[u][1][1] = cvt_pk_bf16(sv[2][2], sv[2][3]);
      pd[u][1][2] = cvt_pk_bf16(sv[3][0], sv[3][1]);
      pd[u][1][3] = cvt_pk_bf16(sv[3][2], sv[3][3]);
    }

    // PV for both subtiles, V-frags shared
    __builtin_amdgcn_s_setprio(1);
#pragma unroll
    for (int t = 0; t < 2; t++) {
      bf16x8 pa0 = __builtin_bit_cast(bf16x8, *reinterpret_cast<u16x8*>(pd[0][t]));
      bf16x8 pa1 = __builtin_bit_cast(bf16x8, *reinterpret_cast<u16x8*>(pd[1][t]));
#pragma unroll
      for (int n = 0; n < 4; n++) {
        int d = n * 16 + r0;
        int swzb = d & 56;
        const u16x4 lo = *reinterpret_cast<const u16x4*>(&Vs[d][(t * 32 + kq * 4) ^ swzb]);
        const u16x4 hi = *reinterpret_cast<const u16x4*>(&Vs[d][(t * 32 + 16 + kq * 4) ^ swzb]);
        u16x8 vbw;
#pragma unroll
        for (int i = 0; i < 4; i++) { vbw[i] = lo[i]; vbw[4 + i] = hi[i]; }
        bf16x8 vb = __builtin_bit_cast(bf16x8, vbw);
        accO[0][n] = __builtin_amdgcn_mfma_f32_16x16x32_bf16(pa0, vb, accO[0][n], 0, 0, 0);
        accO[1][n] = __builtin_amdgcn_mfma_f32_16x16x32_bf16(pa1, vb, accO[1][n], 0, 0, 0);
      }
    }
    __builtin_amdgcn_s_setprio(0);
  };

  int buf = 0;
  LOADT(0);
  WRITET(0);
  size_t koff = (size_t)64 * C3;
  const int nkt = (q0 + 128) >> 6;
  for (int kt = 0; kt < nkt - 1; kt++) {
    __syncthreads();
    LOADT(koff);
    koff += (size_t)64 * C3;
    TILE(buf, kt * 64);
    WRITET(buf ^ 1);
    buf ^= 1;
  }
  __syncthreads();
  TILE(buf, (nkt - 1) * 64);

  // epilogue
#pragma unroll
  for (int u = 0; u < 2; u++) {
    const int qbu = u ? qb1 : qb0;
    float l = ls4[u][0] + ls4[u][1] + ls4[u][2] + ls4[u][3];
    l += __shfl_xor(l, 16);
    l += __shfl_xor(l, 32);
    float lr[4];
#pragma unroll
    for (int r = 0; r < 4; r++) lr[r] = 1.f / __shfl(l, kq * 4 + r);
#pragma unroll
    for (int n = 0; n < 4; n++) {
#pragma unroll
      for (int r = 0; r < 4; r++) {
        int qrow = qbu + kq * 4 + r;
        float v = accO[u][n][r] * lr[r];
        att[((size_t)b * T + qrow) * C + h * 64 + n * 16 + r0] = f2bf(v);
      }
    }
  }
}

extern "C" void kernel_launch(void* const* d_in, const int* in_sizes, int n_in,
                              void* d_out, int out_size, void* d_ws, size_t ws_size,
                              hipStream_t stream) {
  const float* x = (const float*)d_in[0];
  const float* w_qkv = (const float*)d_in[1];
  const float* b_qkv = (const float*)d_in[2];
  const float* w_proj = (const float*)d_in[3];
  const float* b_proj = (const float*)d_in[4];

  constexpr int B = 4, T = 2048, C = 1024, C3 = 3072;
  constexpr int M = B * T;  // 8192
  constexpr float SCL = 0.125f * LOG2E;

  unsigned short* x_bf = (unsigned short*)d_ws;            // M*C
  unsigned short* wqkvT = x_bf + (size_t)M * C;            // C3*C
  unsigned short* wprojT = wqkvT + (size_t)C3 * C;         // C*C
  unsigned short* qkv = wprojT + (size_t)C * C;            // M*C3
  unsigned short* att = qkv + (size_t)M * C3;              // M*C
  float* bias_s = (float*)(att + (size_t)M * C);           // C3 floats

  hipLaunchKernelGGL(k_convert, dim3(2048), dim3(256), 0, stream, x, x_bf, M * C / 4);
  hipLaunchKernelGGL(k_transpose, dim3(C3 / 32, C / 32), dim3(256), 0, stream,
                     w_qkv, wqkvT, C, C3, C, SCL);
  hipLaunchKernelGGL(k_transpose, dim3(C / 32, C / 32), dim3(256), 0, stream,
                     w_proj, wprojT, C, C, 0, 1.f);
  hipLaunchKernelGGL(k_scale_bias, dim3((C3 + 255) / 256), dim3(256), 0, stream,
                     b_qkv, bias_s, C3, C, SCL);
  hipLaunchKernelGGL((k_gemm<true>), dim3(M / 128, C3 / 128), dim3(256), 0, stream,
                     x_bf, wqkvT, bias_s, (void*)qkv, M, C3, C);
  hipLaunchKernelGGL(k_flash, dim3(64, 16), dim3(256), 0, stream, qkv, att, T);
  hipLaunchKernelGGL((k_gemm<false>), dim3(M / 128, C / 128), dim3(256), 0, stream,
                     att, wprojT, b_proj, d_out, M, C, C);
}